// Round 5
// baseline (475.883 us; speedup 1.0000x reference)
//
#include <hip/hip_runtime.h>
#include <hip/hip_bf16.h>

#define S_DIM 128
#define N_PTS 384
#define CM    64
#define C_DIM 32
#define CZ    128
#define NC    (N_PTS*C_DIM)   // 12288

typedef __attribute__((ext_vector_type(8)))  __bf16 bf16x8;
typedef __attribute__((ext_vector_type(16))) float  f32x16;
typedef unsigned short u16;
typedef unsigned int   u32;

__device__ __forceinline__ bf16x8 lds_frag(const void* base, int byteoff){
  union { uint4 u; bf16x8 v; } x;
  x.u = *(const uint4*)((const char*)base + byteoff);
  return x.v;
}
__device__ __forceinline__ u16 bf16bits(float f){
  union { float f; u32 u; } x; x.f = f;
  u32 r = (x.u + 0x7fff + ((x.u >> 16) & 1)) >> 16;   // RNE
  return (u16)r;
}

// ---------------- kernel 0: W [1024,128] (f32) -> Wt_perm [128 z][1024 mem-idx] (bf16) ------
__global__ __launch_bounds__(256) void k_wt(const float* __restrict__ w_out,
                                            __hip_bfloat16* __restrict__ wt){
  int o = blockIdx.x*256 + threadIdx.x;     // 131072 total
  int z = o >> 10, mi = o & 1023;
  int e = mi & 7, j = (mi >> 3) & 3, hi = (mi >> 5) & 1, Q = mi >> 6;
  int ks = Q*4 + j;
  int pos = ks*16 + hi*8 + e;
  int c = ((pos >> 7) << 2) | (pos & 3);
  int d = (pos >> 2) & 31;
  int k = c*32 + d;
  wt[o] = (__hip_bfloat16)w_out[k*CZ + z];
}

// ---------------- kernel 0b: norm[i][j] = sum_s mask[s,i]*mask[s,j] ----------------
__global__ __launch_bounds__(384) void k_norm(const float* __restrict__ mask,
                                              float* __restrict__ nrm_g){
  int i = blockIdx.x, j = threadIdx.x;
  float a = 0.f;
  #pragma unroll 8
  for (int s = 0; s < S_DIM; ++s)
    a += mask[s*N_PTS + i] * mask[s*N_PTS + j];
  nrm_g[i*N_PTS + j] = a;
}

// ---------------- kernel 1: LN + projections via MFMA, coalesced transposed outputs --------
__global__ __launch_bounds__(512) void k_lnproj(
    const float* __restrict__ msa, const float* __restrict__ mask,
    const float* __restrict__ gamma, const float* __restrict__ beta,
    const float* __restrict__ wa, const float* __restrict__ wb,
    __hip_bfloat16* __restrict__ A_ws, __hip_bfloat16* __restrict__ B_ws){
  __shared__ union {
    u16   X[128*64];     // 16KB bf16 LN'd [s][m]
    float T[64*128];     // 32KB f32 [col][s]
  } sh;
  __shared__ float ln_mk[128];

  const int tid = threadIdx.x, w = tid >> 6, l = tid & 63;
  const int hi = l >> 5, ln = l & 31;
  const int n = blockIdx.x;

  if (tid < 128) ln_mk[tid] = mask[tid*N_PTS + n];

  const float g  = gamma[l];
  const float be = beta[l];

  #pragma unroll
  for (int t = 0; t < 16; ++t){
    int s = w*16 + t;
    float x = msa[((size_t)s*N_PTS + n)*CM + l];
    float sum = x;
    #pragma unroll
    for (int m = 1; m < 64; m <<= 1) sum += __shfl_xor(sum, m, 64);
    float mu = sum * (1.0f/64.0f);
    float dx = x - mu;
    float vs = dx*dx;
    #pragma unroll
    for (int m = 1; m < 64; m <<= 1) vs += __shfl_xor(vs, m, 64);
    float rstd = rsqrtf(vs*(1.0f/64.0f) + 1e-5f);
    float xn = dx*rstd*g + be;
    *(u16*)((char*)sh.X + s*128 + ((l*2) ^ ((s&7)<<4))) = bf16bits(xn);
  }
  __syncthreads();

  const int mb = w >> 1, mat = w & 1;
  const float* W = mat ? wb : wa;
  f32x16 pacc;
  #pragma unroll
  for (int r = 0; r < 16; ++r) pacc[r] = 0.f;
  #pragma unroll
  for (int ks = 0; ks < 4; ++ks){
    int srow = mb*32 + ln;
    bf16x8 aF = lds_frag(sh.X, srow*128 + (((ks*32 + hi*16)) ^ ((srow&7)<<4)));
    union { u16 s[8]; bf16x8 v; } bx;
    #pragma unroll
    for (int e = 0; e < 8; ++e){
      int m = ks*16 + hi*8 + e;
      bx.s[e] = bf16bits(W[m*C_DIM + ln]);
    }
    pacc = __builtin_amdgcn_mfma_f32_32x32x16_bf16(aF, bx.v, pacc, 0, 0, 0);
  }
  __syncthreads();

  const int col = mat*32 + ln;
  #pragma unroll
  for (int r = 0; r < 16; ++r){
    int rr = (r & 3) + ((r >> 2) << 3) + (hi << 2);
    int s = mb*32 + rr;
    *(float*)((char*)sh.T + col*512 + ((s*4) ^ ((col&7)<<4))) = pacc[r] * ln_mk[s];
  }
  __syncthreads();

  {
    int col2 = tid >> 3, sc = tid & 7;
    __hip_bfloat16* O = (col2 < 32) ? A_ws : B_ws;
    int row = n*C_DIM + (col2 & 31);
    u16 outv[16];
    #pragma unroll
    for (int q = 0; q < 4; ++q){
      union { uint4 u4; float f[4]; } rd;
      rd.u4 = *(const uint4*)((const char*)sh.T + col2*512 + ((sc*64 + q*16) ^ ((col2&7)<<4)));
      #pragma unroll
      for (int e = 0; e < 4; ++e) outv[q*4 + e] = bf16bits(rd.f[e]);
    }
    uint4 pk0, pk1;
    u32* pw = (u32*)&pk0;
    #pragma unroll
    for (int q = 0; q < 4; ++q) pw[q] = (u32)outv[2*q] | ((u32)outv[2*q+1] << 16);
    u32* pw1 = (u32*)&pk1;
    #pragma unroll
    for (int q = 0; q < 4; ++q) pw1[q] = (u32)outv[8 + 2*q] | ((u32)outv[8 + 2*q+1] << 16);
    *(uint4*)((char*)O + (size_t)row*256 + sc*32)      = pk0;
    *(uint4*)((char*)O + (size_t)row*256 + sc*32 + 16) = pk1;
  }
}

// ---------------- kernel 2: fused ----------------
__global__ __launch_bounds__(512, 1) void k_fused(
    const __hip_bfloat16* __restrict__ A_ws, const __hip_bfloat16* __restrict__ B_ws,
    const __hip_bfloat16* __restrict__ Wt,  const float* __restrict__ b_out,
    const float* __restrict__ nrm_g, float* __restrict__ out){
  __shared__ union {
    struct { u16 A[256*128]; u16 B[256*128]; } s1;
    struct { u16 P[64*1024]; } s2;
  } sh;
  __shared__ float nrm[64];

  const int tid = threadIdx.x;
  const int w = tid >> 6, l = tid & 63;
  const int hi = l >> 5, ln = l & 31;
  const int bi = blockIdx.x, bj = blockIdx.y;

  // ---- staging loads (issue first) ----
  const char* Asrc = (const char*)(A_ws + (size_t)bi*256*S_DIM);
  const char* Bsrc = (const char*)(B_ws + (size_t)bj*256*S_DIM);
  u16* shA = sh.s1.A;
  u16* shB = sh.s1.B;
  #pragma unroll
  for (int it = 0; it < 8; ++it){
    int o = (it*512 + tid) * 16;
    int row = o >> 8, kb = o & 255;
    int dst = row*256 + (kb ^ ((row & 15) << 4));
    *(uint4*)((char*)shA + dst) = *(const uint4*)(Asrc + o);
    *(uint4*)((char*)shB + dst) = *(const uint4*)(Bsrc + o);
  }

  // ---- early stage-C prefetch: nrm + first 8 Wt frags (land during stage B) ----
  if (tid < 64){
    int i = bi*8 + (tid >> 3), jj = bj*8 + (tid & 7);
    nrm[tid] = nrm_g[i*N_PTS + jj];
  }
  const int cr = w >> 2, cc = w & 3;
  const char* wbase = (const char*)Wt + (size_t)(cc*32 + ln)*2048 + hi*64;
  uint4 wreg[8];
  #pragma unroll
  for (int u = 0; u < 8; ++u)
    wreg[u] = *(const uint4*)(wbase + (u >> 2)*128 + (u & 3)*16);
  __syncthreads();

  // ---- stage B ----
  const int wr = w >> 2, wc = w & 3;
  f32x16 acc[4][2];
  #pragma unroll
  for (int mb = 0; mb < 4; ++mb)
    #pragma unroll
    for (int nb = 0; nb < 2; ++nb)
      #pragma unroll
      for (int r = 0; r < 16; ++r) acc[mb][nb][r] = 0.f;

  #pragma unroll
  for (int ks = 0; ks < 8; ++ks){
    const int k0b = ks*32 + hi*16;
    bf16x8 aF[4], bF[2];
    #pragma unroll
    for (int mb = 0; mb < 4; ++mb){
      int m = wr*128 + mb*32 + ln;
      aF[mb] = lds_frag(shA, m*256 + (k0b ^ ((m & 15) << 4)));
    }
    #pragma unroll
    for (int nb = 0; nb < 2; ++nb){
      int n = wc*64 + nb*32 + ln;
      bF[nb] = lds_frag(shB, n*256 + (k0b ^ ((n & 15) << 4)));
    }
    #pragma unroll
    for (int mb = 0; mb < 4; ++mb)
      #pragma unroll
      for (int nb = 0; nb < 2; ++nb)
        acc[mb][nb] = __builtin_amdgcn_mfma_f32_32x32x16_bf16(aF[mb], bF[nb], acc[mb][nb], 0, 0, 0);
  }
  __syncthreads();

  // ---- write P ----
  char* shP = (char*)sh.s2.P;
  #pragma unroll
  for (int mb = 0; mb < 4; ++mb)
    #pragma unroll
    for (int nb = 0; nb < 2; ++nb){
      int p = (wr*4 + mb)*8 + (wc*2 + nb);
      int base = p*2048, sw = (p & 15) << 4;
      #pragma unroll
      for (int g = 0; g < 4; ++g){
        u32 lo   = (u32)bf16bits(acc[mb][nb][4*g + 0]) | ((u32)bf16bits(acc[mb][nb][4*g + 1]) << 16);
        u32 hi32 = (u32)bf16bits(acc[mb][nb][4*g + 2]) | ((u32)bf16bits(acc[mb][nb][4*g + 3]) << 16);
        uint2 v; v.x = lo; v.y = hi32;
        int off = ((2*g + hi)*256 + ln*8) ^ sw;
        *(uint2*)(shP + base + off) = v;
      }
    }
  __syncthreads();

  // ---- stage C ----
  f32x16 zca, zcb;
  #pragma unroll
  for (int r = 0; r < 16; ++r){ zca[r] = 0.f; zcb[r] = 0.f; }

  const char* prow = shP + (cr*32 + ln)*2048;
  const int sw2 = (ln & 15) << 4;

  #pragma unroll
  for (int kb = 0; kb < 8; ++kb){
    #pragma unroll
    for (int u = 0; u < 8; ++u){
      int ks = kb*8 + u;
      bf16x8 aF = lds_frag(prow, (ks*32 + hi*16) ^ sw2);
      union { uint4 q; bf16x8 v; } bx; bx.q = wreg[u];
      if (u & 1) zcb = __builtin_amdgcn_mfma_f32_32x32x16_bf16(aF, bx.v, zcb, 0, 0, 0);
      else       zca = __builtin_amdgcn_mfma_f32_32x32x16_bf16(aF, bx.v, zca, 0, 0, 0);
      if (kb < 7){
        int kn = ks + 8;
        wreg[u] = *(const uint4*)(wbase + (kn >> 2)*128 + (kn & 3)*16);
      }
    }
  }
  #pragma unroll
  for (int r = 0; r < 16; ++r) zca[r] += zcb[r];

  // ---- epilogue ----
  const int z = cc*32 + ln;
  const float bo = b_out[z];
  #pragma unroll
  for (int r = 0; r < 16; ++r){
    int p = cr*32 + (r & 3) + ((r >> 2) << 3) + (hi << 2);
    int i = bi*8 + (p >> 3), j = bj*8 + (p & 7);
    float val = (zca[r] + bo) / (nrm[p] + 0.001f);
    out[((size_t)i*N_PTS + j)*CZ + z] = val;
  }
}

// ---------------- ablation: {staging + stageB + P-write} x 6 passes ----------------
// Instrumentation only: duration read from rocprof. Visible in top-5 iff front*6 > k_fused.
__global__ __launch_bounds__(512, 1) void k_ablfront(
    const __hip_bfloat16* __restrict__ A_ws, const __hip_bfloat16* __restrict__ B_ws,
    float* __restrict__ cks_g){
  __shared__ union {
    struct { u16 A[256*128]; u16 B[256*128]; } s1;
    struct { u16 P[64*1024]; } s2;
  } sh;

  const int tid = threadIdx.x;
  const int w = tid >> 6, l = tid & 63;
  const int hi = l >> 5, ln = l & 31;
  const int bi = blockIdx.x, bj = blockIdx.y;
  const int wr = w >> 2, wc = w & 3;
  const int cr = w >> 2;

  const char* Asrc = (const char*)(A_ws + (size_t)bi*256*S_DIM);
  const char* Bsrc = (const char*)(B_ws + (size_t)bj*256*S_DIM);
  u16* shA = sh.s1.A;
  u16* shB = sh.s1.B;
  char* shP = (char*)sh.s2.P;
  const int sw2 = (ln & 15) << 4;

  float cks = 0.f;
  #pragma unroll 1
  for (int pass = 0; pass < 6; ++pass){
    // staging (src offset per pass prevents CSE; same instruction count)
    #pragma unroll
    for (int it = 0; it < 8; ++it){
      int o = (it*512 + tid) * 16;
      int row = o >> 8, kb = o & 255;
      int dst = row*256 + (kb ^ ((row & 15) << 4));
      *(uint4*)((char*)shA + dst) = *(const uint4*)(Asrc + o + pass*64);
      *(uint4*)((char*)shB + dst) = *(const uint4*)(Bsrc + o + pass*64);
    }
    __syncthreads();

    // stage B
    f32x16 acc[4][2];
    #pragma unroll
    for (int mb = 0; mb < 4; ++mb)
      #pragma unroll
      for (int nb = 0; nb < 2; ++nb)
        #pragma unroll
        for (int r = 0; r < 16; ++r) acc[mb][nb][r] = 0.f;

    #pragma unroll
    for (int ks = 0; ks < 8; ++ks){
      const int k0b = ks*32 + hi*16;
      bf16x8 aF[4], bF[2];
      #pragma unroll
      for (int mb = 0; mb < 4; ++mb){
        int m = wr*128 + mb*32 + ln;
        aF[mb] = lds_frag(shA, m*256 + (k0b ^ ((m & 15) << 4)));
      }
      #pragma unroll
      for (int nb = 0; nb < 2; ++nb){
        int n = wc*64 + nb*32 + ln;
        bF[nb] = lds_frag(shB, n*256 + (k0b ^ ((n & 15) << 4)));
      }
      #pragma unroll
      for (int mb = 0; mb < 4; ++mb)
        #pragma unroll
        for (int nb = 0; nb < 2; ++nb)
          acc[mb][nb] = __builtin_amdgcn_mfma_f32_32x32x16_bf16(aF[mb], bF[nb], acc[mb][nb], 0, 0, 0);
    }
    __syncthreads();

    // P write
    #pragma unroll
    for (int mb = 0; mb < 4; ++mb)
      #pragma unroll
      for (int nb = 0; nb < 2; ++nb){
        int p = (wr*4 + mb)*8 + (wc*2 + nb);
        int base = p*2048, sw = (p & 15) << 4;
        #pragma unroll
        for (int g = 0; g < 4; ++g){
          u32 lo   = (u32)bf16bits(acc[mb][nb][4*g + 0]) | ((u32)bf16bits(acc[mb][nb][4*g + 1]) << 16);
          u32 hi32 = (u32)bf16bits(acc[mb][nb][4*g + 2]) | ((u32)bf16bits(acc[mb][nb][4*g + 3]) << 16);
          uint2 v; v.x = lo; v.y = hi32;
          int off = ((2*g + hi)*256 + ln*8) ^ sw;
          *(uint2*)(shP + base + off) = v;
        }
      }
    __syncthreads();

    // consume this pass's P (keeps every pass live)
    bf16x8 f = lds_frag(shP + (cr*32 + ln)*2048, (pass*32) ^ sw2);
    cks += (float)f[0];
  }
  if (l == 0) cks_g[(bj*48 + bi)*8 + w] = cks;
}

extern "C" void kernel_launch(void* const* d_in, const int* in_sizes, int n_in,
                              void* d_out, int out_size, void* d_ws, size_t ws_size,
                              hipStream_t stream) {
  (void)in_sizes; (void)n_in; (void)out_size; (void)ws_size;
  const float* msa   = (const float*)d_in[0];
  const float* mask  = (const float*)d_in[1];
  const float* gamma = (const float*)d_in[2];
  const float* beta  = (const float*)d_in[3];
  const float* wa    = (const float*)d_in[4];
  const float* wb    = (const float*)d_in[5];
  const float* wout  = (const float*)d_in[6];
  const float* bout  = (const float*)d_in[7];

  __hip_bfloat16* A_ws = (__hip_bfloat16*)d_ws;              // [12288][128] bf16
  __hip_bfloat16* B_ws = A_ws + (size_t)NC*S_DIM;            // [12288][128] bf16
  __hip_bfloat16* Wt   = B_ws + (size_t)NC*S_DIM;            // [128][1024] bf16 (pos-permuted)
  float* nrm_g = (float*)(Wt + (size_t)CZ*1024);             // [384][384] f32
  float* cks_g = nrm_g + (size_t)N_PTS*N_PTS;                // ablation sink
  float* outp  = (float*)d_out;                              // [384][384][128] f32

  k_wt<<<512, 256, 0, stream>>>(wout, Wt);
  k_norm<<<N_PTS, 384, 0, stream>>>(mask, nrm_g);
  k_lnproj<<<N_PTS, 512, 0, stream>>>(msa, mask, gamma, beta, wa, wb, A_ws, B_ws);
  dim3 g2(48, 48, 1);
  k_fused<<<g2, 512, 0, stream>>>(A_ws, B_ws, Wt, bout, nrm_g, outp);
  k_ablfront<<<g2, 512, 0, stream>>>(A_ws, B_ws, cks_g);
}

// Round 6
// 266.027 us; speedup vs baseline: 1.7889x; 1.7889x over previous
//
#include <hip/hip_runtime.h>
#include <hip/hip_bf16.h>

#define S_DIM 128
#define N_PTS 384
#define CM    64
#define C_DIM 32
#define CZ    128
#define NC    (N_PTS*C_DIM)   // 12288

typedef __attribute__((ext_vector_type(8)))  __bf16 bf16x8;
typedef __attribute__((ext_vector_type(16))) float  f32x16;
typedef unsigned short u16;
typedef unsigned int   u32;

__device__ __forceinline__ bf16x8 lds_frag(const void* base, int byteoff){
  union { uint4 u; bf16x8 v; } x;
  x.u = *(const uint4*)((const char*)base + byteoff);
  return x.v;
}
__device__ __forceinline__ u16 bf16bits(float f){
  union { float f; u32 u; } x; x.f = f;
  u32 r = (x.u + 0x7fff + ((x.u >> 16) & 1)) >> 16;   // RNE
  return (u16)r;
}

// ---------------- kernel 0: W [1024,128] (f32) -> Wt_perm [128 z][1024 mem-idx] (bf16) ------
// mem idx mi: e=mi&7, j=(mi>>3)&3, hi=(mi>>5)&1, Q=mi>>6 ; ks=Q*4+j ; pos=ks*16+hi*8+e
// pos -> original k: c = ((pos>>7)<<2)|(pos&3), d = (pos>>2)&31, k = c*32+d
__global__ __launch_bounds__(256) void k_wt(const float* __restrict__ w_out,
                                            __hip_bfloat16* __restrict__ wt){
  int o = blockIdx.x*256 + threadIdx.x;     // 131072 total
  int z = o >> 10, mi = o & 1023;
  int e = mi & 7, j = (mi >> 3) & 3, hi = (mi >> 5) & 1, Q = mi >> 6;
  int ks = Q*4 + j;
  int pos = ks*16 + hi*8 + e;
  int c = ((pos >> 7) << 2) | (pos & 3);
  int d = (pos >> 2) & 31;
  int k = c*32 + d;
  wt[o] = (__hip_bfloat16)w_out[k*CZ + z];
}

// ---------------- kernel 0b: norm[i][j] = sum_s mask[s,i]*mask[s,j] ----------------
__global__ __launch_bounds__(384) void k_norm(const float* __restrict__ mask,
                                              float* __restrict__ nrm_g){
  int i = blockIdx.x, j = threadIdx.x;
  float a = 0.f;
  #pragma unroll 8
  for (int s = 0; s < S_DIM; ++s)
    a += mask[s*N_PTS + i] * mask[s*N_PTS + j];
  nrm_g[i*N_PTS + j] = a;
}

// ---------------- kernel 1: LN + projections via MFMA, coalesced transposed outputs --------
__global__ __launch_bounds__(512) void k_lnproj(
    const float* __restrict__ msa, const float* __restrict__ mask,
    const float* __restrict__ gamma, const float* __restrict__ beta,
    const float* __restrict__ wa, const float* __restrict__ wb,
    __hip_bfloat16* __restrict__ A_ws, __hip_bfloat16* __restrict__ B_ws){
  __shared__ union {
    u16   X[128*64];     // 16KB bf16 LN'd [s][m]
    float T[64*128];     // 32KB f32 [col][s]
  } sh;
  __shared__ float ln_mk[128];

  const int tid = threadIdx.x, w = tid >> 6, l = tid & 63;
  const int hi = l >> 5, ln = l & 31;
  const int n = blockIdx.x;

  if (tid < 128) ln_mk[tid] = mask[tid*N_PTS + n];

  const float g  = gamma[l];
  const float be = beta[l];

  #pragma unroll
  for (int t = 0; t < 16; ++t){
    int s = w*16 + t;
    float x = msa[((size_t)s*N_PTS + n)*CM + l];
    float sum = x;
    #pragma unroll
    for (int m = 1; m < 64; m <<= 1) sum += __shfl_xor(sum, m, 64);
    float mu = sum * (1.0f/64.0f);
    float dx = x - mu;
    float vs = dx*dx;
    #pragma unroll
    for (int m = 1; m < 64; m <<= 1) vs += __shfl_xor(vs, m, 64);
    float rstd = rsqrtf(vs*(1.0f/64.0f) + 1e-5f);
    float xn = dx*rstd*g + be;
    *(u16*)((char*)sh.X + s*128 + ((l*2) ^ ((s&7)<<4))) = bf16bits(xn);
  }
  __syncthreads();

  const int mb = w >> 1, mat = w & 1;
  const float* W = mat ? wb : wa;
  f32x16 pacc;
  #pragma unroll
  for (int r = 0; r < 16; ++r) pacc[r] = 0.f;
  #pragma unroll
  for (int ks = 0; ks < 4; ++ks){
    int srow = mb*32 + ln;
    bf16x8 aF = lds_frag(sh.X, srow*128 + (((ks*32 + hi*16)) ^ ((srow&7)<<4)));
    union { u16 s[8]; bf16x8 v; } bx;
    #pragma unroll
    for (int e = 0; e < 8; ++e){
      int m = ks*16 + hi*8 + e;
      bx.s[e] = bf16bits(W[m*C_DIM + ln]);
    }
    pacc = __builtin_amdgcn_mfma_f32_32x32x16_bf16(aF, bx.v, pacc, 0, 0, 0);
  }
  __syncthreads();

  const int col = mat*32 + ln;
  #pragma unroll
  for (int r = 0; r < 16; ++r){
    int rr = (r & 3) + ((r >> 2) << 3) + (hi << 2);
    int s = mb*32 + rr;
    *(float*)((char*)sh.T + col*512 + ((s*4) ^ ((col&7)<<4))) = pacc[r] * ln_mk[s];
  }
  __syncthreads();

  {
    int col2 = tid >> 3, sc = tid & 7;
    __hip_bfloat16* O = (col2 < 32) ? A_ws : B_ws;
    int row = n*C_DIM + (col2 & 31);
    u16 outv[16];
    #pragma unroll
    for (int q = 0; q < 4; ++q){
      union { uint4 u4; float f[4]; } rd;
      rd.u4 = *(const uint4*)((const char*)sh.T + col2*512 + ((sc*64 + q*16) ^ ((col2&7)<<4)));
      #pragma unroll
      for (int e = 0; e < 4; ++e) outv[q*4 + e] = bf16bits(rd.f[e]);
    }
    uint4 pk0, pk1;
    u32* pw = (u32*)&pk0;
    #pragma unroll
    for (int q = 0; q < 4; ++q) pw[q] = (u32)outv[2*q] | ((u32)outv[2*q+1] << 16);
    u32* pw1 = (u32*)&pk1;
    #pragma unroll
    for (int q = 0; q < 4; ++q) pw1[q] = (u32)outv[8 + 2*q] | ((u32)outv[8 + 2*q+1] << 16);
    *(uint4*)((char*)O + (size_t)row*256 + sc*32)      = pk0;
    *(uint4*)((char*)O + (size_t)row*256 + sc*32 + 16) = pk1;
  }
}

// ---------------- kernel 2: fused, 8x4 tile, 2 blocks/CU ----------------
// grid (48, 96), 512 threads (8 waves as 2x4).
// Stage B: M=256 (8i x 32c), N=128 (4j x 32d), K=128 staged in two 64-halves.
// Stage C: M=32 pairs, N=128 z, K=1024; wave (cr=K-half, cc=z-block); LDS reduce.
__global__ __launch_bounds__(512, 4) void k_fused(
    const __hip_bfloat16* __restrict__ A_ws, const __hip_bfloat16* __restrict__ B_ws,
    const __hip_bfloat16* __restrict__ Wt,  const float* __restrict__ b_out,
    const float* __restrict__ nrm_g, float* __restrict__ out){
  __shared__ union {
    struct { u16 Ah[256*64]; u16 Bh[128*64]; } s1;   // 32KB + 16KB half-slabs
    char P[65536];                                   // 32 pairs x 2048B (pos layout)
  } sh;
  __shared__ float nrm[32];

  const int tid = threadIdx.x;
  const int w = tid >> 6, l = tid & 63;
  const int hi = l >> 5, ln = l & 31;
  const int bi = blockIdx.x, bj = blockIdx.y;
  const int wr = w >> 2, wc = w & 3;      // B: (M-half, j-block) ; C: (K-half, z-block)

  const char* Asrc = (const char*)A_ws + (size_t)bi*256*256;   // 256 rows x 256B
  const char* Bsrc = (const char*)B_ws + (size_t)bj*128*256;   // 128 rows x 256B

  const int ra  = tid >> 1, ira = (tid & 1)*64;   // A staging: 64B/thread
  const int rb  = tid >> 2, irb = (tid & 3)*32;   // B staging: 32B/thread

  // ---- P0: issue h0 loads + nrm ----
  uint4 la[4], lb[2];
  #pragma unroll
  for (int q = 0; q < 4; ++q) la[q] = *(const uint4*)(Asrc + ra*256 + ira + q*16);
  #pragma unroll
  for (int q = 0; q < 2; ++q) lb[q] = *(const uint4*)(Bsrc + rb*256 + irb + q*16);
  if (tid < 32) nrm[tid] = nrm_g[(bi*8 + (tid>>2))*N_PTS + bj*4 + (tid&3)];

  // ---- P1: write h0 ----
  u16* Ah = sh.s1.Ah;  u16* Bh = sh.s1.Bh;
  #pragma unroll
  for (int q = 0; q < 4; ++q){
    int ir = ira + q*16;
    *(uint4*)((char*)Ah + ra*128 + (ir ^ ((ra&7)<<4))) = la[q];
  }
  #pragma unroll
  for (int q = 0; q < 2; ++q){
    int ir = irb + q*16;
    *(uint4*)((char*)Bh + rb*128 + (ir ^ ((rb&7)<<4))) = lb[q];
  }
  __syncthreads();

  // ---- P2: issue h1 loads; stage-B h0 ----
  #pragma unroll
  for (int q = 0; q < 4; ++q) la[q] = *(const uint4*)(Asrc + ra*256 + 128 + ira + q*16);
  #pragma unroll
  for (int q = 0; q < 2; ++q) lb[q] = *(const uint4*)(Bsrc + rb*256 + 128 + irb + q*16);

  f32x16 acc[4];
  #pragma unroll
  for (int mb = 0; mb < 4; ++mb)
    #pragma unroll
    for (int r = 0; r < 16; ++r) acc[mb][r] = 0.f;

  #pragma unroll
  for (int ks = 0; ks < 4; ++ks){
    int k0 = ks*32 + hi*16;
    int n2 = wc*32 + ln;
    bf16x8 bF = lds_frag(Bh, n2*128 + (k0 ^ ((n2&7)<<4)));
    #pragma unroll
    for (int mb = 0; mb < 4; ++mb){
      int m = wr*128 + mb*32 + ln;
      bf16x8 aF = lds_frag(Ah, m*128 + (k0 ^ ((m&7)<<4)));
      acc[mb] = __builtin_amdgcn_mfma_f32_32x32x16_bf16(aF, bF, acc[mb], 0, 0, 0);
    }
  }
  __syncthreads();

  // ---- P3: write h1 ----
  #pragma unroll
  for (int q = 0; q < 4; ++q){
    int ir = ira + q*16;
    *(uint4*)((char*)Ah + ra*128 + (ir ^ ((ra&7)<<4))) = la[q];
  }
  #pragma unroll
  for (int q = 0; q < 2; ++q){
    int ir = irb + q*16;
    *(uint4*)((char*)Bh + rb*128 + (ir ^ ((rb&7)<<4))) = lb[q];
  }
  __syncthreads();

  // ---- P4: Wt 8-deep prefetch; stage-B h1 ----
  // Wt row byte layout within this wave's K-half: step ks2 -> (ks2>>2)*128 + (ks2&3)*16
  const char* wbase = (const char*)Wt + (size_t)(wc*32 + ln)*2048 + wr*1024 + hi*64;
  uint4 wreg[8];
  #pragma unroll
  for (int u = 0; u < 8; ++u)
    wreg[u] = *(const uint4*)(wbase + (u>>2)*128 + (u&3)*16);

  #pragma unroll
  for (int ks = 0; ks < 4; ++ks){
    int k0 = ks*32 + hi*16;
    int n2 = wc*32 + ln;
    bf16x8 bF = lds_frag(Bh, n2*128 + (k0 ^ ((n2&7)<<4)));
    #pragma unroll
    for (int mb = 0; mb < 4; ++mb){
      int m = wr*128 + mb*32 + ln;
      bf16x8 aF = lds_frag(Ah, m*128 + (k0 ^ ((m&7)<<4)));
      acc[mb] = __builtin_amdgcn_mfma_f32_32x32x16_bf16(aF, bF, acc[mb], 0, 0, 0);
    }
  }
  __syncthreads();

  // ---- P5: write P (pos layout) ----
  // pair p = (wr*4+mb)*4 + wc ; c=(r&3)+8*(r>>2)+4*hi ; d=ln
  // byte = p*2048 + (((c>>2)*256 + d*8 + (c&3)*2) ^ ((p&15)<<4))
  char* shP = sh.P;
  #pragma unroll
  for (int mb = 0; mb < 4; ++mb){
    int p = (wr*4 + mb)*4 + wc;
    int base = p*2048, sw = (p & 15) << 4;
    #pragma unroll
    for (int g = 0; g < 4; ++g){
      u32 lo   = (u32)bf16bits(acc[mb][4*g + 0]) | ((u32)bf16bits(acc[mb][4*g + 1]) << 16);
      u32 hi32 = (u32)bf16bits(acc[mb][4*g + 2]) | ((u32)bf16bits(acc[mb][4*g + 3]) << 16);
      uint2 v; v.x = lo; v.y = hi32;
      int off = ((2*g + hi)*256 + ln*8) ^ sw;
      *(uint2*)(shP + base + off) = v;
    }
  }
  __syncthreads();

  // ---- P6: stage C: z[p][z'] partial over K-half wr ----
  f32x16 zca, zcb;
  #pragma unroll
  for (int r = 0; r < 16; ++r){ zca[r] = 0.f; zcb[r] = 0.f; }

  const char* prow = shP + ln*2048;     // row p = ln (all 32 pairs)
  const int sw2 = (ln & 15) << 4;
  const int kbase = wr*1024;            // byte base of this K-half in pos space

  #pragma unroll
  for (int kb = 0; kb < 4; ++kb){
    #pragma unroll
    for (int u = 0; u < 8; ++u){
      int ks2 = kb*8 + u;
      bf16x8 aF = lds_frag(prow, (kbase + ks2*32 + hi*16) ^ sw2);
      union { uint4 q; bf16x8 v; } bx; bx.q = wreg[u];
      if (u & 1) zcb = __builtin_amdgcn_mfma_f32_32x32x16_bf16(aF, bx.v, zcb, 0, 0, 0);
      else       zca = __builtin_amdgcn_mfma_f32_32x32x16_bf16(aF, bx.v, zca, 0, 0, 0);
      if (kb < 3){
        int kn = ks2 + 8;
        wreg[u] = *(const uint4*)(wbase + (kn>>2)*128 + (kn&3)*16);
      }
    }
  }
  #pragma unroll
  for (int r = 0; r < 16; ++r) zca[r] += zcb[r];
  __syncthreads();   // all P reads done; P space free

  // ---- P7: cross-K-half reduce through P space, epilogue by cr=0 waves ----
  float* red = (float*)sh.P;   // [32 p][128 z] f32 = 16KB
  if (wr == 1){
    #pragma unroll
    for (int r = 0; r < 16; ++r){
      int p = (r & 3) + ((r >> 2) << 3) + (hi << 2);
      red[p*128 + wc*32 + ln] = zca[r];
    }
  }
  __syncthreads();
  if (wr == 0){
    const int z = wc*32 + ln;
    const float bo = b_out[z];
    #pragma unroll
    for (int r = 0; r < 16; ++r){
      int p = (r & 3) + ((r >> 2) << 3) + (hi << 2);
      float val = (zca[r] + red[p*128 + z] + bo) / (nrm[p] + 0.001f);
      int i = bi*8 + (p >> 2), j = bj*4 + (p & 3);
      out[((size_t)i*N_PTS + j)*CZ + z] = val;
    }
  }
}

extern "C" void kernel_launch(void* const* d_in, const int* in_sizes, int n_in,
                              void* d_out, int out_size, void* d_ws, size_t ws_size,
                              hipStream_t stream) {
  (void)in_sizes; (void)n_in; (void)out_size; (void)ws_size;
  const float* msa   = (const float*)d_in[0];
  const float* mask  = (const float*)d_in[1];
  const float* gamma = (const float*)d_in[2];
  const float* beta  = (const float*)d_in[3];
  const float* wa    = (const float*)d_in[4];
  const float* wb    = (const float*)d_in[5];
  const float* wout  = (const float*)d_in[6];
  const float* bout  = (const float*)d_in[7];

  __hip_bfloat16* A_ws = (__hip_bfloat16*)d_ws;              // [12288][128] bf16
  __hip_bfloat16* B_ws = A_ws + (size_t)NC*S_DIM;            // [12288][128] bf16
  __hip_bfloat16* Wt   = B_ws + (size_t)NC*S_DIM;            // [128][1024] bf16 (pos-permuted)
  float* nrm_g = (float*)(Wt + (size_t)CZ*1024);             // [384][384] f32
  float* outp  = (float*)d_out;                              // [384][384][128] f32

  k_wt<<<512, 256, 0, stream>>>(wout, Wt);
  k_norm<<<N_PTS, 384, 0, stream>>>(mask, nrm_g);
  k_lnproj<<<N_PTS, 512, 0, stream>>>(msa, mask, gamma, beta, wa, wb, A_ws, B_ws);
  dim3 g2(48, 96, 1);
  k_fused<<<g2, 512, 0, stream>>>(A_ws, B_ws, Wt, bout, nrm_g, outp);
}

// Round 7
// 159.864 us; speedup vs baseline: 2.9768x; 1.6641x over previous
//
#include <hip/hip_runtime.h>
#include <hip/hip_bf16.h>

#define S_DIM 128
#define N_PTS 384
#define CM    64
#define C_DIM 32
#define CZ    128
#define NC    (N_PTS*C_DIM)   // 12288

typedef __attribute__((ext_vector_type(8)))  __bf16 bf16x8;
typedef __attribute__((ext_vector_type(16))) float  f32x16;
typedef unsigned short u16;
typedef unsigned int   u32;

__device__ __forceinline__ bf16x8 lds_frag(const void* base, int byteoff){
  union { uint4 u; bf16x8 v; } x;
  x.u = *(const uint4*)((const char*)base + byteoff);
  return x.v;
}
__device__ __forceinline__ u16 bf16bits(float f){
  union { float f; u32 u; } x; x.f = f;
  u32 r = (x.u + 0x7fff + ((x.u >> 16) & 1)) >> 16;   // RNE
  return (u16)r;
}

// ---------------- kernel 0: W [1024,128] (f32) -> Wt_perm [128 z][1024 mem-idx] (bf16) ------
// mem idx mi: e=mi&7, j=(mi>>3)&3, hi=(mi>>5)&1, Q=mi>>6 ; ks=Q*4+j ; pos=ks*16+hi*8+e
// pos -> original k: c = ((pos>>7)<<2)|(pos&3), d = (pos>>2)&31, k = c*32+d
__global__ __launch_bounds__(256) void k_wt(const float* __restrict__ w_out,
                                            __hip_bfloat16* __restrict__ wt){
  int o = blockIdx.x*256 + threadIdx.x;     // 131072 total
  int z = o >> 10, mi = o & 1023;
  int e = mi & 7, j = (mi >> 3) & 3, hi = (mi >> 5) & 1, Q = mi >> 6;
  int ks = Q*4 + j;
  int pos = ks*16 + hi*8 + e;
  int c = ((pos >> 7) << 2) | (pos & 3);
  int d = (pos >> 2) & 31;
  int k = c*32 + d;
  wt[o] = (__hip_bfloat16)w_out[k*CZ + z];
}

// ---------------- kernel 0b: norm[i][j] = sum_s mask[s,i]*mask[s,j] ----------------
__global__ __launch_bounds__(384) void k_norm(const float* __restrict__ mask,
                                              float* __restrict__ nrm_g){
  int i = blockIdx.x, j = threadIdx.x;
  float a = 0.f;
  #pragma unroll 8
  for (int s = 0; s < S_DIM; ++s)
    a += mask[s*N_PTS + i] * mask[s*N_PTS + j];
  nrm_g[i*N_PTS + j] = a;
}

// ---------------- kernel 1: LN + projections via MFMA, coalesced transposed outputs --------
__global__ __launch_bounds__(512) void k_lnproj(
    const float* __restrict__ msa, const float* __restrict__ mask,
    const float* __restrict__ gamma, const float* __restrict__ beta,
    const float* __restrict__ wa, const float* __restrict__ wb,
    __hip_bfloat16* __restrict__ A_ws, __hip_bfloat16* __restrict__ B_ws){
  __shared__ union {
    u16   X[128*64];     // 16KB bf16 LN'd [s][m]
    float T[64*128];     // 32KB f32 [col][s]
  } sh;
  __shared__ float ln_mk[128];

  const int tid = threadIdx.x, w = tid >> 6, l = tid & 63;
  const int hi = l >> 5, ln = l & 31;
  const int n = blockIdx.x;

  if (tid < 128) ln_mk[tid] = mask[tid*N_PTS + n];

  const float g  = gamma[l];
  const float be = beta[l];

  #pragma unroll
  for (int t = 0; t < 16; ++t){
    int s = w*16 + t;
    float x = msa[((size_t)s*N_PTS + n)*CM + l];
    float sum = x;
    #pragma unroll
    for (int m = 1; m < 64; m <<= 1) sum += __shfl_xor(sum, m, 64);
    float mu = sum * (1.0f/64.0f);
    float dx = x - mu;
    float vs = dx*dx;
    #pragma unroll
    for (int m = 1; m < 64; m <<= 1) vs += __shfl_xor(vs, m, 64);
    float rstd = rsqrtf(vs*(1.0f/64.0f) + 1e-5f);
    float xn = dx*rstd*g + be;
    *(u16*)((char*)sh.X + s*128 + ((l*2) ^ ((s&7)<<4))) = bf16bits(xn);
  }
  __syncthreads();

  const int mb = w >> 1, mat = w & 1;
  const float* W = mat ? wb : wa;
  f32x16 pacc;
  #pragma unroll
  for (int r = 0; r < 16; ++r) pacc[r] = 0.f;
  #pragma unroll
  for (int ks = 0; ks < 4; ++ks){
    int srow = mb*32 + ln;
    bf16x8 aF = lds_frag(sh.X, srow*128 + (((ks*32 + hi*16)) ^ ((srow&7)<<4)));
    union { u16 s[8]; bf16x8 v; } bx;
    #pragma unroll
    for (int e = 0; e < 8; ++e){
      int m = ks*16 + hi*8 + e;
      bx.s[e] = bf16bits(W[m*C_DIM + ln]);
    }
    pacc = __builtin_amdgcn_mfma_f32_32x32x16_bf16(aF, bx.v, pacc, 0, 0, 0);
  }
  __syncthreads();

  const int col = mat*32 + ln;
  #pragma unroll
  for (int r = 0; r < 16; ++r){
    int rr = (r & 3) + ((r >> 2) << 3) + (hi << 2);
    int s = mb*32 + rr;
    *(float*)((char*)sh.T + col*512 + ((s*4) ^ ((col&7)<<4))) = pacc[r] * ln_mk[s];
  }
  __syncthreads();

  {
    int col2 = tid >> 3, sc = tid & 7;
    __hip_bfloat16* O = (col2 < 32) ? A_ws : B_ws;
    int row = n*C_DIM + (col2 & 31);
    u16 outv[16];
    #pragma unroll
    for (int q = 0; q < 4; ++q){
      union { uint4 u4; float f[4]; } rd;
      rd.u4 = *(const uint4*)((const char*)sh.T + col2*512 + ((sc*64 + q*16) ^ ((col2&7)<<4)));
      #pragma unroll
      for (int e = 0; e < 4; ++e) outv[q*4 + e] = bf16bits(rd.f[e]);
    }
    uint4 pk0, pk1;
    u32* pw = (u32*)&pk0;
    #pragma unroll
    for (int q = 0; q < 4; ++q) pw[q] = (u32)outv[2*q] | ((u32)outv[2*q+1] << 16);
    u32* pw1 = (u32*)&pk1;
    #pragma unroll
    for (int q = 0; q < 4; ++q) pw1[q] = (u32)outv[8 + 2*q] | ((u32)outv[8 + 2*q+1] << 16);
    *(uint4*)((char*)O + (size_t)row*256 + sc*32)      = pk0;
    *(uint4*)((char*)O + (size_t)row*256 + sc*32 + 16) = pk1;
  }
}

// ---------------- kernel 2: fused, 8x8 tile, R5 structure + restructured stage C ----------
// grid (48,48), 512 threads (8 waves).
// Stage B: waves (wr,wc) 2x4, 256x256 over K=128 (unchanged from R5 — conflict-free).
// Stage C: waves (kh = K-half, cc = z-quarter); each wave M=64 (zc0/zc1), K=512 slice;
//          batched 8-rounds-of-4 with wreg[8] two-bank lookahead; f32 reduce via P space.
__global__ __launch_bounds__(512, 2) void k_fused(
    const __hip_bfloat16* __restrict__ A_ws, const __hip_bfloat16* __restrict__ B_ws,
    const __hip_bfloat16* __restrict__ Wt,  const float* __restrict__ b_out,
    const float* __restrict__ nrm_g, float* __restrict__ out){
  __shared__ union {
    struct { u16 A[256*128]; u16 B[256*128]; } s1;   // 64KB + 64KB slabs (256B rows)
    struct { u16 P[64*1024]; } s2;                   // 128KB P (pos layout, swizzled)
  } sh;
  __shared__ float nrm[64];

  const int tid = threadIdx.x;
  const int w = tid >> 6, l = tid & 63;
  const int hi = l >> 5, ln = l & 31;
  const int bi = blockIdx.x, bj = blockIdx.y;

  // ---- staging loads (issue first) ----
  const char* Asrc = (const char*)(A_ws + (size_t)bi*256*S_DIM);
  const char* Bsrc = (const char*)(B_ws + (size_t)bj*256*S_DIM);
  u16* shA = sh.s1.A;
  u16* shB = sh.s1.B;
  #pragma unroll
  for (int it = 0; it < 8; ++it){
    int o = (it*512 + tid) * 16;
    int row = o >> 8, kb = o & 255;
    int dst = row*256 + (kb ^ ((row & 15) << 4));
    *(uint4*)((char*)shA + dst) = *(const uint4*)(Asrc + o);
    *(uint4*)((char*)shB + dst) = *(const uint4*)(Bsrc + o);
  }

  // ---- early stage-C prefetch: nrm + first 8 k-steps of this wave's Wt slice ----
  if (tid < 64){
    int i = bi*8 + (tid >> 3), jj = bj*8 + (tid & 7);
    nrm[tid] = nrm_g[i*N_PTS + jj];
  }
  const int kh = w >> 2, cc = w & 3;      // stage-C role
  const char* wbase = (const char*)Wt + (size_t)(cc*32 + ln)*2048 + kh*1024 + hi*64;
  uint4 wreg[8];
  #pragma unroll
  for (int u = 0; u < 8; ++u)
    wreg[u] = *(const uint4*)(wbase + (u>>2)*128 + (u&3)*16);
  __syncthreads();

  // ---- stage B (unchanged from R5) ----
  const int wr = w >> 2, wc = w & 3;
  f32x16 acc[4][2];
  #pragma unroll
  for (int mb = 0; mb < 4; ++mb)
    #pragma unroll
    for (int nb = 0; nb < 2; ++nb)
      #pragma unroll
      for (int r = 0; r < 16; ++r) acc[mb][nb][r] = 0.f;

  #pragma unroll
  for (int ks = 0; ks < 8; ++ks){
    const int k0b = ks*32 + hi*16;
    bf16x8 aF[4], bF[2];
    #pragma unroll
    for (int mb = 0; mb < 4; ++mb){
      int m = wr*128 + mb*32 + ln;
      aF[mb] = lds_frag(shA, m*256 + (k0b ^ ((m & 15) << 4)));
    }
    #pragma unroll
    for (int nb = 0; nb < 2; ++nb){
      int n = wc*64 + nb*32 + ln;
      bF[nb] = lds_frag(shB, n*256 + (k0b ^ ((n & 15) << 4)));
    }
    #pragma unroll
    for (int mb = 0; mb < 4; ++mb)
      #pragma unroll
      for (int nb = 0; nb < 2; ++nb)
        acc[mb][nb] = __builtin_amdgcn_mfma_f32_32x32x16_bf16(aF[mb], bF[nb], acc[mb][nb], 0, 0, 0);
  }
  __syncthreads();

  // ---- write P (pos layout, b64-packed) ----
  char* shP = (char*)sh.s2.P;
  #pragma unroll
  for (int mb = 0; mb < 4; ++mb)
    #pragma unroll
    for (int nb = 0; nb < 2; ++nb){
      int p = (wr*4 + mb)*8 + (wc*2 + nb);
      int base = p*2048, sw = (p & 15) << 4;
      #pragma unroll
      for (int g = 0; g < 4; ++g){
        u32 lo   = (u32)bf16bits(acc[mb][nb][4*g + 0]) | ((u32)bf16bits(acc[mb][nb][4*g + 1]) << 16);
        u32 hi32 = (u32)bf16bits(acc[mb][nb][4*g + 2]) | ((u32)bf16bits(acc[mb][nb][4*g + 3]) << 16);
        uint2 v; v.x = lo; v.y = hi32;
        int off = ((2*g + hi)*256 + ln*8) ^ sw;
        *(uint2*)(shP + base + off) = v;
      }
    }
  __syncthreads();

  // ---- stage C: z[p][z'] partials over K-half kh; M=64 (zc0: p=ln, zc1: p=32+ln) ----
  f32x16 zc0, zc1;
  #pragma unroll
  for (int r = 0; r < 16; ++r){ zc0[r] = 0.f; zc1[r] = 0.f; }

  const char* prow0 = shP + (size_t)ln*2048;
  const char* prow1 = shP + (size_t)(32 + ln)*2048;
  const int sw2 = (ln & 15) << 4;
  const int kbase = kh*1024;     // byte base of K-half in pos space

  #pragma unroll
  for (int rd = 0; rd < 8; ++rd){
    bf16x8 a0[4], a1[4];
    #pragma unroll
    for (int u = 0; u < 4; ++u){
      int off = (kbase + (rd*4 + u)*32 + hi*16) ^ sw2;
      a0[u] = lds_frag(prow0, off);
      a1[u] = lds_frag(prow1, off);
    }
    #pragma unroll
    for (int u = 0; u < 4; ++u){
      union { uint4 q; bf16x8 v; } bx; bx.q = wreg[(rd & 1)*4 + u];
      zc0 = __builtin_amdgcn_mfma_f32_32x32x16_bf16(a0[u], bx.v, zc0, 0, 0, 0);
      zc1 = __builtin_amdgcn_mfma_f32_32x32x16_bf16(a1[u], bx.v, zc1, 0, 0, 0);
      if (rd < 6){
        int kn = (rd + 2)*4 + u;
        wreg[(rd & 1)*4 + u] = *(const uint4*)(wbase + (kn>>2)*128 + (kn&3)*16);
      }
    }
  }
  __syncthreads();   // all P reads complete; P space free

  // ---- cross-K-half reduce through P space; epilogue by kh=0 waves ----
  float* red = (float*)sh.s2.P;   // [64 p][128 z] f32 = 32KB
  if (kh == 1){
    #pragma unroll
    for (int r = 0; r < 16; ++r){
      int pr = (r & 3) + ((r >> 2) << 3) + (hi << 2);
      red[pr*128 + cc*32 + ln]       = zc0[r];
      red[(32 + pr)*128 + cc*32 + ln] = zc1[r];
    }
  }
  __syncthreads();
  if (kh == 0){
    const int z = cc*32 + ln;
    const float bo = b_out[z];
    #pragma unroll
    for (int r = 0; r < 16; ++r){
      int pr = (r & 3) + ((r >> 2) << 3) + (hi << 2);
      {
        int p = pr;
        float v = (zc0[r] + red[p*128 + z] + bo) / (nrm[p] + 0.001f);
        int i = bi*8 + (p >> 3), j = bj*8 + (p & 7);
        out[((size_t)i*N_PTS + j)*CZ + z] = v;
      }
      {
        int p = 32 + pr;
        float v = (zc1[r] + red[p*128 + z] + bo) / (nrm[p] + 0.001f);
        int i = bi*8 + (p >> 3), j = bj*8 + (p & 7);
        out[((size_t)i*N_PTS + j)*CZ + z] = v;
      }
    }
  }
}

extern "C" void kernel_launch(void* const* d_in, const int* in_sizes, int n_in,
                              void* d_out, int out_size, void* d_ws, size_t ws_size,
                              hipStream_t stream) {
  (void)in_sizes; (void)n_in; (void)out_size; (void)ws_size;
  const float* msa   = (const float*)d_in[0];
  const float* mask  = (const float*)d_in[1];
  const float* gamma = (const float*)d_in[2];
  const float* beta  = (const float*)d_in[3];
  const float* wa    = (const float*)d_in[4];
  const float* wb    = (const float*)d_in[5];
  const float* wout  = (const float*)d_in[6];
  const float* bout  = (const float*)d_in[7];

  __hip_bfloat16* A_ws = (__hip_bfloat16*)d_ws;              // [12288][128] bf16
  __hip_bfloat16* B_ws = A_ws + (size_t)NC*S_DIM;            // [12288][128] bf16
  __hip_bfloat16* Wt   = B_ws + (size_t)NC*S_DIM;            // [128][1024] bf16 (pos-permuted)
  float* nrm_g = (float*)(Wt + (size_t)CZ*1024);             // [384][384] f32
  float* outp  = (float*)d_out;                              // [384][384][128] f32

  k_wt<<<512, 256, 0, stream>>>(wout, Wt);
  k_norm<<<N_PTS, 384, 0, stream>>>(mask, nrm_g);
  k_lnproj<<<N_PTS, 512, 0, stream>>>(msa, mask, gamma, beta, wa, wb, A_ws, B_ws);
  dim3 g2(48, 48, 1);
  k_fused<<<g2, 512, 0, stream>>>(A_ws, B_ws, Wt, bout, nrm_g, outp);
}